// Round 6
// baseline (297.424 us; speedup 1.0000x reference)
//
#include <hip/hip_runtime.h>

#define FDIM 128
#define NBMAX 128     // max dst-buckets per graph (N<=65536 -> <=128 buckets of 512)
#define CAPB 10240    // per-bucket capacity in binned[] (E/NB ~ 8163, 23 sigma slack)

typedef short short8 __attribute__((ext_vector_type(8)));
typedef float f32x4 __attribute__((ext_vector_type(4)));

static __device__ __forceinline__ unsigned short f2bf(float f) {
    unsigned u = __float_as_uint(f);
    u += 0x7FFF + ((u >> 16) & 1);          // round-to-nearest-even
    return (unsigned short)(u >> 16);
}
static __device__ __forceinline__ float bf2f(unsigned short h) {
    return __uint_as_float(((unsigned)h) << 16);
}

// ---------------- fp32 -> bf16 convert (+ zero gCnt in block 0) ----------------
__global__ __launch_bounds__(256) void convert_kernel(
    const float* __restrict__ x, ushort* __restrict__ xb, int n4,
    int* __restrict__ gCnt, int nb3)
{
    if (blockIdx.x == 0) {
        for (int k = threadIdx.x; k < nb3; k += 256) gCnt[k] = 0;
    }
    int i = blockIdx.x * 256 + threadIdx.x;
    if (i >= n4) return;
    float4 v = reinterpret_cast<const float4*>(x)[i];
    ushort4 o = { f2bf(v.x), f2bf(v.y), f2bf(v.z), f2bf(v.w) };
    reinterpret_cast<ushort4*>(xb)[i] = o;
}

// ---------------- pack [Wl;Wr] (256 x FOUT) into MFMA B-fragment order ----------------
__global__ __launch_bounds__(256) void pack_kernel(
    const float* __restrict__ Wl, const float* __restrict__ Wr,
    ushort* __restrict__ Wp, int FOUT)
{
    int JT = FOUT >> 4;
    int idx = blockIdx.x * 256 + threadIdx.x;
    if (idx >= 8 * JT * 64) return;
    int lane = idx & 63;
    int jt = (idx >> 6) % JT;
    int kt = (idx >> 6) / JT;
    int kbase = kt * 32 + (lane >> 4) * 8;
    int j = jt * 16 + (lane & 15);
    const float* W = (kbase < 128) ? Wl : Wr;
    int kb = kbase & 127;
    ushort tmp[8];
#pragma unroll
    for (int t = 0; t < 8; ++t) tmp[t] = f2bf(W[(size_t)(kb + t) * FOUT + j]);
    *reinterpret_cast<uint4*>(Wp + (size_t)idx * 8) = *reinterpret_cast<uint4*>(tmp);
}

// ---------------- pass 1: bin edges by dst bucket (counting sort in LDS) ----------------
// binned[(g*NB+b)*CAPB + k] = ((dst&511)<<16) | src   (requires N <= 65536)
__global__ __launch_bounds__(256) void bin_kernel(
    const int* __restrict__ ei1, const int* __restrict__ ei2, const int* __restrict__ ei3,
    int* __restrict__ gCnt, unsigned* __restrict__ binned,
    int E, int NB, int bpg)
{
    __shared__ int hist[NBMAX];
    __shared__ int excl[NBMAX];
    __shared__ int cursor[NBMAX];
    __shared__ int gbase[NBMAX];
    __shared__ unsigned stag[4096];

    const int g = blockIdx.x / bpg;
    const int c = blockIdx.x % bpg;
    const int* ei = (g == 0) ? ei1 : (g == 1) ? ei2 : ei3;
    const int e0 = c * 4096;
    const int chunk = min(4096, E - e0);
    const int t = threadIdx.x;

    if (t < NB) hist[t] = 0;
    __syncthreads();
    for (int i = t; i < chunk; i += 256)
        atomicAdd(&hist[ei[E + e0 + i] >> 9], 1);
    __syncthreads();
    // exclusive scan over NB<=128 buckets: one wave, 2 adjacent elems per lane
    if (t < 64) {
        int a = (2 * t     < NB) ? hist[2 * t]     : 0;
        int b = (2 * t + 1 < NB) ? hist[2 * t + 1] : 0;
        int s = a + b, incl = s;
#pragma unroll
        for (int d = 1; d < 64; d <<= 1) {
            int x = __shfl_up(incl, d);
            if (t >= d) incl += x;
        }
        int ex = incl - s;
        if (2 * t     < NB) { excl[2 * t]     = ex;     cursor[2 * t]     = ex; }
        if (2 * t + 1 < NB) { excl[2 * t + 1] = ex + a; cursor[2 * t + 1] = ex + a; }
    }
    __syncthreads();
    if (t < NB) {
        int cnt = hist[t];
        gbase[t] = cnt ? atomicAdd(&gCnt[g * NB + t], cnt) : 0;
    }
    __syncthreads();
    // counting-sort the chunk into LDS
    for (int i = t; i < chunk; i += 256) {
        int src = ei[e0 + i];
        int dst = ei[E + e0 + i];
        int bk = dst >> 9;
        int pl = atomicAdd(&cursor[bk], 1);
        stag[pl] = ((unsigned)(dst & 511) << 16) | (unsigned)src;
    }
    __syncthreads();
    // linear, run-contiguous writeback (binary search bucket of position i)
    for (int i = t; i < chunk; i += 256) {
        int lo = 0, hi = NB - 1;
        while (lo < hi) { int mid = (lo + hi + 1) >> 1; if (excl[mid] <= i) lo = mid; else hi = mid - 1; }
        int off = gbase[lo] + (i - excl[lo]);
        if (off < CAPB)
            binned[(size_t)(g * NB + lo) * CAPB + off] = stag[i];
    }
}

// ---------------- pass 2: scan bucket counts (M = 3*NB <= 512) ----------------
__global__ __launch_bounds__(512) void scanb_kernel(
    const int* __restrict__ gCnt, int* __restrict__ gScan,
    int* __restrict__ rowptr, int M, int N)
{
    __shared__ int s[512];
    int t = threadIdx.x;
    int v = (t < M) ? gCnt[t] : 0;
    s[t] = v;
    __syncthreads();
    for (int d = 1; d < 512; d <<= 1) {
        int x = (t >= d) ? s[t - d] : 0;
        __syncthreads();
        s[t] += x;
        __syncthreads();
    }
    if (t < M) gScan[t] = s[t] - v;
    if (t == M - 1) { gScan[M] = s[t]; rowptr[(size_t)3 * N] = s[t]; }
}

// ---------------- pass 3: per-bucket CSR fill (L1-local scatter) ----------------
__global__ __launch_bounds__(256) void fill2_kernel(
    const unsigned* __restrict__ binned, const int* __restrict__ gCnt,
    const int* __restrict__ gScan, int* __restrict__ rowptr,
    ushort* __restrict__ colu, int N, int NB)
{
    __shared__ int hist[512];
    __shared__ int cursor[512];
    __shared__ int wsum[4];

    const int g = blockIdx.x / NB, b = blockIdx.x % NB;
    const int gb = g * NB + b;
    const int t = threadIdx.x;
    const int n0 = b << 9;
    const int NL = min(512, N - n0);
    const int cnt = min(gCnt[gb], CAPB);
    const size_t ebase = (size_t)gb * CAPB;
    const int colBase = gScan[gb];

    hist[t] = 0; hist[t + 256] = 0;
    __syncthreads();
    for (int e = t; e < cnt; e += 256)
        atomicAdd(&hist[binned[ebase + e] >> 16], 1);
    __syncthreads();
    // scan 512 elems: 4 waves x (2 adjacent elems per lane)
    const int lane = t & 63, w = t >> 6;
    int a = hist[2 * t], bb = hist[2 * t + 1];
    int s2 = a + bb, incl = s2;
#pragma unroll
    for (int d = 1; d < 64; d <<= 1) {
        int x = __shfl_up(incl, d);
        if (lane >= d) incl += x;
    }
    if (lane == 63) wsum[w] = incl;
    __syncthreads();
    int woff = 0;
    for (int ww = 0; ww < w; ++ww) woff += wsum[ww];
    int ex = woff + incl - s2;                 // exclusive prefix for elem 2t
    if (2 * t     < NL) rowptr[(size_t)g * N + n0 + 2 * t]     = colBase + ex;
    if (2 * t + 1 < NL) rowptr[(size_t)g * N + n0 + 2 * t + 1] = colBase + ex + a;
    cursor[2 * t] = ex; cursor[2 * t + 1] = ex + a;
    __syncthreads();
    for (int e = t; e < cnt; e += 256) {
        unsigned u = binned[ebase + e];
        int pl = atomicAdd(&cursor[u >> 16], 1);
        colu[colBase + pl] = (ushort)(u & 0xFFFFu);
    }
}

// ---------------- fused gather + MFMA GEMM ----------------
// per 64-node block: gather mean into LDS slots 0..15, stage self rows into
// slots 16..31, then out = act([mean||xin] @ [Wl;Wr] + b) [+ xin residual]
template<int FOUT, bool RELU, bool RES, bool OUTF>
__global__ __launch_bounds__(256) void fused_gemm(
    const ushort* __restrict__ xin, const int* __restrict__ rp,
    const ushort* __restrict__ col, const ushort* __restrict__ Wp,
    const float* __restrict__ bias, ushort* __restrict__ outb,
    float* __restrict__ outf, int N)
{
    constexpr int JT = FOUT / 16;
    __shared__ __align__(16) ushort sA[64 * 256];   // 64 rows x 32 slots(16B), XOR-swizzled
    const int tid = threadIdx.x;
    const int n0 = blockIdx.x * 64;
    const int lane = tid & 63;
    const int w = tid >> 6;

    // stage self features into slots 16..31
#pragma unroll
    for (int it = 0; it < 4; ++it) {
        int idx = it * 256 + tid;            // 0..1023 = 64 rows x 16 slots
        int r = idx >> 4, s16 = idx & 15;
        int n = n0 + r; if (n >= N) n = N - 1;
        uint4 v = *reinterpret_cast<const uint4*>(xin + ((size_t)n << 7) + (s16 << 3));
        int s = 16 + s16;
        int sp = (s & 24) | ((s ^ r) & 7);
        *reinterpret_cast<uint4*>(&sA[(r << 8) + (sp << 3)]) = v;
    }

    // gather neighbor mean into slots 0..15: wave w owns rows w*16..w*16+15,
    // lane accumulates features {2*lane, 2*lane+1}
    for (int i = 0; i < 16; ++i) {
        int r = w * 16 + i;
        int n = n0 + r; if (n >= N) n = N - 1;
        int beg = rp[n], end = rp[n + 1];
        float a0x = 0, a0y = 0, a1x = 0, a1y = 0, a2x = 0, a2y = 0, a3x = 0, a3y = 0;
        int e = beg;
        for (; e + 4 <= end; e += 4) {
            int s0 = col[e], s1 = col[e + 1], s2 = col[e + 2], s3 = col[e + 3];
            unsigned u0 = *reinterpret_cast<const unsigned*>(xin + ((size_t)s0 << 7) + lane * 2);
            unsigned u1 = *reinterpret_cast<const unsigned*>(xin + ((size_t)s1 << 7) + lane * 2);
            unsigned u2 = *reinterpret_cast<const unsigned*>(xin + ((size_t)s2 << 7) + lane * 2);
            unsigned u3 = *reinterpret_cast<const unsigned*>(xin + ((size_t)s3 << 7) + lane * 2);
            a0x += __uint_as_float(u0 << 16); a0y += __uint_as_float(u0 & 0xFFFF0000u);
            a1x += __uint_as_float(u1 << 16); a1y += __uint_as_float(u1 & 0xFFFF0000u);
            a2x += __uint_as_float(u2 << 16); a2y += __uint_as_float(u2 & 0xFFFF0000u);
            a3x += __uint_as_float(u3 << 16); a3y += __uint_as_float(u3 & 0xFFFF0000u);
        }
        for (; e < end; ++e) {
            int s = col[e];
            unsigned u = *reinterpret_cast<const unsigned*>(xin + ((size_t)s << 7) + lane * 2);
            a0x += __uint_as_float(u << 16); a0y += __uint_as_float(u & 0xFFFF0000u);
        }
        float sx = (a0x + a1x) + (a2x + a3x);
        float sy = (a0y + a1y) + (a2y + a3y);
        int deg = end - beg;
        float inv = 1.0f / (float)(deg > 1 ? deg : 1);
        unsigned o = (unsigned)f2bf(sx * inv) | ((unsigned)f2bf(sy * inv) << 16);
        int s = lane >> 2;                                 // slot 0..15
        int sp = (s & 24) | ((s ^ r) & 7);
        *reinterpret_cast<unsigned*>(&sA[(r << 8) + (sp << 3) + 2 * (lane & 3)]) = o;
    }
    __syncthreads();

    const int rloc = w * 16 + (lane & 15);
    const int q = lane >> 4;

    f32x4 acc[JT];
#pragma unroll
    for (int jt = 0; jt < JT; ++jt) acc[jt] = (f32x4){0.f, 0.f, 0.f, 0.f};

#pragma unroll
    for (int kt = 0; kt < 8; ++kt) {
        int s = kt * 4 + q;
        int sp = (s & 24) | ((s ^ rloc) & 7);
        short8 a = *reinterpret_cast<const short8*>(&sA[(rloc << 8) + (sp << 3)]);
#pragma unroll
        for (int jt = 0; jt < JT; ++jt) {
            short8 b = *reinterpret_cast<const short8*>(Wp + ((size_t)((kt * JT + jt) * 64 + lane) << 3));
            acc[jt] = __builtin_amdgcn_mfma_f32_16x16x32_bf16(a, b, acc[jt], 0, 0, 0);
        }
    }

#pragma unroll
    for (int jt = 0; jt < JT; ++jt) {
        int j = jt * 16 + (lane & 15);
        float bj = bias[j];
#pragma unroll
        for (int reg = 0; reg < 4; ++reg) {
            int n = n0 + w * 16 + q * 4 + reg;
            if (n < N) {
                float v = acc[jt][reg] + bj;
                if (RELU) v = fmaxf(v, 0.f);
                if (RES)  v += bf2f(xin[((size_t)n << 7) + j]);
                if (OUTF) outf[(size_t)n * FOUT + j] = v;
                else      outb[(size_t)n * FOUT + j] = f2bf(v);
            }
        }
    }
}

extern "C" void kernel_launch(void* const* d_in, const int* in_sizes, int n_in,
                              void* d_out, int out_size, void* d_ws, size_t ws_size,
                              hipStream_t stream) {
    const float* x   = (const float*)d_in[0];
    const int*   ei1 = (const int*)d_in[1];
    const int*   ei2 = (const int*)d_in[2];
    const int*   ei3 = (const int*)d_in[3];
    const float* Wl1 = (const float*)d_in[4];
    const float* Wr1 = (const float*)d_in[5];
    const float* b1  = (const float*)d_in[6];
    const float* Wl2 = (const float*)d_in[7];
    const float* Wr2 = (const float*)d_in[8];
    const float* b2  = (const float*)d_in[9];
    const float* Wl3 = (const float*)d_in[10];
    const float* Wr3 = (const float*)d_in[11];
    const float* b3  = (const float*)d_in[12];
    float* out = (float*)d_out;

    const int N = in_sizes[0] / FDIM;   // 50000
    const int E = in_sizes[1] / 2;      // 800000
    const int NB = (N + 511) >> 9;      // 98 buckets of 512 nodes

    auto al = [](size_t v) { return (v + 255) & ~(size_t)255; };
    char* ws = (char*)d_ws;
    ushort* xb   = (ushort*)ws;   ws += al((size_t)N * FDIM * 2);
    ushort* hb   = (ushort*)ws;   ws += al((size_t)N * FDIM * 2);
    ushort* h2   = (ushort*)ws;   ws += al((size_t)N * FDIM * 2);
    ushort* Wp1  = (ushort*)ws;   ws += al((size_t)8 * 8 * 64 * 8 * 2);
    ushort* Wp2  = (ushort*)ws;   ws += al((size_t)8 * 8 * 64 * 8 * 2);
    ushort* Wp3  = (ushort*)ws;   ws += al((size_t)8 * 4 * 64 * 8 * 2);
    int*     rowptr = (int*)ws;   ws += al((size_t)(3 * N + 1) * 4);
    int*     gCnt   = (int*)ws;   ws += al((size_t)(3 * NB) * 4);
    int*     gScan  = (int*)ws;   ws += al((size_t)(3 * NB + 1) * 4);
    unsigned* binned = (unsigned*)ws; ws += al((size_t)3 * NB * CAPB * 4);
    ushort*  colu   = (ushort*)ws;

    const int bpg = (E + 4095) / 4096;
    const int gemmBlocks = (N + 63) / 64;

    // prep: bf16 features (+gCnt zero) + packed weights
    convert_kernel<<<(N * FDIM / 4 + 255) / 256, 256, 0, stream>>>(
        x, xb, N * FDIM / 4, gCnt, 3 * NB);
    pack_kernel<<<16, 256, 0, stream>>>(Wl1, Wr1, Wp1, 128);
    pack_kernel<<<16, 256, 0, stream>>>(Wl2, Wr2, Wp2, 128);
    pack_kernel<<<8, 256, 0, stream>>>(Wl3, Wr3, Wp3, 64);

    // CSR build for all 3 graphs: bin -> scan -> per-bucket fill
    bin_kernel<<<3 * bpg, 256, 0, stream>>>(ei1, ei2, ei3, gCnt, binned, E, NB, bpg);
    scanb_kernel<<<1, 512, 0, stream>>>(gCnt, gScan, rowptr, 3 * NB, N);
    fill2_kernel<<<3 * NB, 256, 0, stream>>>(binned, gCnt, gScan, rowptr, colu, N, NB);

    // layer 1: hb = relu(mean1@Wl1 + b1 + x@Wr1)
    fused_gemm<128, true, false, false><<<gemmBlocks, 256, 0, stream>>>(
        xb, rowptr, colu, Wp1, b1, hb, nullptr, N);

    // layer 2: h2 = relu(mean2@Wl2 + b2 + hb@Wr2) + hb   (NOT in-place: gather reads hb)
    fused_gemm<128, true, true, false><<<gemmBlocks, 256, 0, stream>>>(
        hb, rowptr + N, colu, Wp2, b2, h2, nullptr, N);

    // layer 3: out = mean3@Wl3 + b3 + h2@Wr3
    fused_gemm<64, false, false, true><<<gemmBlocks, 256, 0, stream>>>(
        h2, rowptr + 2 * N, colu, Wp3, b3, nullptr, out, N);
}

// Round 7
// 222.823 us; speedup vs baseline: 1.3348x; 1.3348x over previous
//
#include <hip/hip_runtime.h>

#define FDIM 128
#define NBMAX 128     // max dst-buckets per graph (N<=65536 -> <=128 buckets of 512)
#define CAPB 10240    // per-bucket capacity in binned[] (E/NB ~ 8163, 23 sigma slack)

typedef short short8 __attribute__((ext_vector_type(8)));
typedef float f32x4 __attribute__((ext_vector_type(4)));

static __device__ __forceinline__ unsigned short f2bf(float f) {
    unsigned u = __float_as_uint(f);
    u += 0x7FFF + ((u >> 16) & 1);          // round-to-nearest-even
    return (unsigned short)(u >> 16);
}
static __device__ __forceinline__ float bf2f(unsigned short h) {
    return __uint_as_float(((unsigned)h) << 16);
}

// ---------------- fp32 -> bf16 convert (+ zero gCnt in block 0) ----------------
__global__ __launch_bounds__(256) void convert_kernel(
    const float* __restrict__ x, ushort* __restrict__ xb, int n4,
    int* __restrict__ gCnt, int nb3)
{
    if (blockIdx.x == 0) {
        for (int k = threadIdx.x; k < nb3; k += 256) gCnt[k] = 0;
    }
    int i = blockIdx.x * 256 + threadIdx.x;
    if (i >= n4) return;
    float4 v = reinterpret_cast<const float4*>(x)[i];
    ushort4 o = { f2bf(v.x), f2bf(v.y), f2bf(v.z), f2bf(v.w) };
    reinterpret_cast<ushort4*>(xb)[i] = o;
}

// ---------------- pack all 3 layers' [Wl;Wr] into MFMA B-fragment order ----------------
// Wp[kt][jt][lane][t] = W[kt*32 + (lane>>4)*8 + t][jt*16 + (lane&15)]  (bf16)
__global__ __launch_bounds__(256) void pack3_kernel(
    const float* __restrict__ Wl1, const float* __restrict__ Wr1,
    const float* __restrict__ Wl2, const float* __restrict__ Wr2,
    const float* __restrict__ Wl3, const float* __restrict__ Wr3,
    ushort* __restrict__ Wp1, ushort* __restrict__ Wp2, ushort* __restrict__ Wp3)
{
    int b = blockIdx.x;
    const float *Wl, *Wr; ushort* Wp; int FOUT, base;
    if (b < 16)      { Wl = Wl1; Wr = Wr1; Wp = Wp1; FOUT = 128; base = b; }
    else if (b < 32) { Wl = Wl2; Wr = Wr2; Wp = Wp2; FOUT = 128; base = b - 16; }
    else             { Wl = Wl3; Wr = Wr3; Wp = Wp3; FOUT = 64;  base = b - 32; }
    int JT = FOUT >> 4;
    int idx = base * 256 + threadIdx.x;
    if (idx >= 8 * JT * 64) return;
    int lane = idx & 63;
    int jt = (idx >> 6) % JT;
    int kt = (idx >> 6) / JT;
    int kbase = kt * 32 + (lane >> 4) * 8;
    int j = jt * 16 + (lane & 15);
    const float* W = (kbase < 128) ? Wl : Wr;
    int kb = kbase & 127;
    ushort tmp[8];
#pragma unroll
    for (int t = 0; t < 8; ++t) tmp[t] = f2bf(W[(size_t)(kb + t) * FOUT + j]);
    *reinterpret_cast<uint4*>(Wp + (size_t)idx * 8) = *reinterpret_cast<uint4*>(tmp);
}

// ---------------- pass 1: bin edges by dst bucket (counting sort in LDS) ----------------
// binned[(g*NB+b)*CAPB + k] = ((dst&511)<<16) | src   (requires N <= 65536)
__global__ __launch_bounds__(256) void bin_kernel(
    const int* __restrict__ ei1, const int* __restrict__ ei2, const int* __restrict__ ei3,
    int* __restrict__ gCnt, unsigned* __restrict__ binned,
    int E, int NB, int bpg)
{
    __shared__ int hist[NBMAX];
    __shared__ int excl[NBMAX];
    __shared__ int cursor[NBMAX];
    __shared__ int gbase[NBMAX];
    __shared__ unsigned stag[4096];

    const int g = blockIdx.x / bpg;
    const int c = blockIdx.x % bpg;
    const int* ei = (g == 0) ? ei1 : (g == 1) ? ei2 : ei3;
    const int e0 = c * 4096;
    const int chunk = min(4096, E - e0);
    const int t = threadIdx.x;

    if (t < NB) hist[t] = 0;
    __syncthreads();
    for (int i = t; i < chunk; i += 256)
        atomicAdd(&hist[ei[E + e0 + i] >> 9], 1);
    __syncthreads();
    // exclusive scan over NB<=128 buckets: one wave, 2 adjacent elems per lane
    if (t < 64) {
        int a = (2 * t     < NB) ? hist[2 * t]     : 0;
        int b = (2 * t + 1 < NB) ? hist[2 * t + 1] : 0;
        int s = a + b, incl = s;
#pragma unroll
        for (int d = 1; d < 64; d <<= 1) {
            int x = __shfl_up(incl, d);
            if (t >= d) incl += x;
        }
        int ex = incl - s;
        if (2 * t     < NB) { excl[2 * t]     = ex;     cursor[2 * t]     = ex; }
        if (2 * t + 1 < NB) { excl[2 * t + 1] = ex + a; cursor[2 * t + 1] = ex + a; }
    }
    __syncthreads();
    if (t < NB) {
        int cnt = hist[t];
        gbase[t] = cnt ? atomicAdd(&gCnt[g * NB + t], cnt) : 0;
    }
    __syncthreads();
    // counting-sort the chunk into LDS
    for (int i = t; i < chunk; i += 256) {
        int src = ei[e0 + i];
        int dst = ei[E + e0 + i];
        int bk = dst >> 9;
        int pl = atomicAdd(&cursor[bk], 1);
        stag[pl] = ((unsigned)(dst & 511) << 16) | (unsigned)src;
    }
    __syncthreads();
    // linear, run-contiguous writeback (binary search bucket of position i)
    for (int i = t; i < chunk; i += 256) {
        int lo = 0, hi = NB - 1;
        while (lo < hi) { int mid = (lo + hi + 1) >> 1; if (excl[mid] <= i) lo = mid; else hi = mid - 1; }
        int off = gbase[lo] + (i - excl[lo]);
        if (off < CAPB)
            binned[(size_t)(g * NB + lo) * CAPB + off] = stag[i];
    }
}

// ---------------- pass 2: per-bucket CSR fill (computes its own global scan) ----------------
__global__ __launch_bounds__(256) void fill2_kernel(
    const unsigned* __restrict__ binned, const int* __restrict__ gCnt,
    int* __restrict__ rowptr, ushort* __restrict__ colu, int N, int NB)
{
    __shared__ int hist[512];
    __shared__ int cursor[512];
    __shared__ int wsum[4];
    __shared__ int sColBase, sTotal;

    const int M = 3 * NB;
    const int gb = blockIdx.x;
    const int g = gb / NB, b = gb % NB;
    const int t = threadIdx.x;
    const int lane = t & 63, w = t >> 6;

    // inline exclusive scan of gCnt[0..M) to find this bucket's colBase
    {
        int v0 = (2 * t     < M) ? gCnt[2 * t]     : 0;
        int v1 = (2 * t + 1 < M) ? gCnt[2 * t + 1] : 0;
        int s2 = v0 + v1, incl = s2;
#pragma unroll
        for (int d = 1; d < 64; d <<= 1) {
            int x = __shfl_up(incl, d);
            if (lane >= d) incl += x;
        }
        if (lane == 63) wsum[w] = incl;
        __syncthreads();
        int woff = 0;
        for (int ww = 0; ww < w; ++ww) woff += wsum[ww];
        int ex = woff + incl - s2;            // exclusive prefix of elem 2t
        if (2 * t     == gb) sColBase = ex;
        if (2 * t + 1 == gb) sColBase = ex + v0;
        if (2 * t     == M - 1) sTotal = ex + v0;
        if (2 * t + 1 == M - 1) sTotal = ex + v0 + v1;
        __syncthreads();
    }
    const int colBase = sColBase;
    if (gb == 0 && t == 0) rowptr[(size_t)3 * N] = sTotal;

    const int n0 = b << 9;
    const int NL = min(512, N - n0);
    const int cnt = min(gCnt[gb], CAPB);
    const size_t ebase = (size_t)gb * CAPB;

    __syncthreads();
    hist[t] = 0; hist[t + 256] = 0;
    __syncthreads();
    for (int e = t; e < cnt; e += 256)
        atomicAdd(&hist[binned[ebase + e] >> 16], 1);
    __syncthreads();
    // scan 512 elems: 4 waves x (2 adjacent elems per lane)
    int a = hist[2 * t], bb = hist[2 * t + 1];
    int s2 = a + bb, incl = s2;
#pragma unroll
    for (int d = 1; d < 64; d <<= 1) {
        int x = __shfl_up(incl, d);
        if (lane >= d) incl += x;
    }
    if (lane == 63) wsum[w] = incl;
    __syncthreads();
    int woff = 0;
    for (int ww = 0; ww < w; ++ww) woff += wsum[ww];
    int ex = woff + incl - s2;                 // exclusive prefix for elem 2t
    if (2 * t     < NL) rowptr[(size_t)g * N + n0 + 2 * t]     = colBase + ex;
    if (2 * t + 1 < NL) rowptr[(size_t)g * N + n0 + 2 * t + 1] = colBase + ex + a;
    cursor[2 * t] = ex; cursor[2 * t + 1] = ex + a;
    __syncthreads();
    for (int e = t; e < cnt; e += 256) {
        unsigned u = binned[ebase + e];
        int pl = atomicAdd(&cursor[u >> 16], 1);
        colu[colBase + pl] = (ushort)(u & 0xFFFFu);
    }
}

// ---------------- gather (bf16): mean[n] = sum x[col[e]] / max(deg,1) ----------------
__global__ __launch_bounds__(256) void gather_kernel(
    const ushort* __restrict__ xb, const int* __restrict__ rp,
    const ushort* __restrict__ col, ushort* __restrict__ mb, int N)
{
    int node = blockIdx.x * 4 + (threadIdx.x >> 6);
    if (node >= N) return;
    int lane = threadIdx.x & 63;
    int beg = rp[node], end = rp[node + 1];
    float a0x = 0, a0y = 0, a1x = 0, a1y = 0, a2x = 0, a2y = 0, a3x = 0, a3y = 0;
    int e = beg;
    for (; e + 4 <= end; e += 4) {
        int s0 = col[e], s1 = col[e + 1], s2 = col[e + 2], s3 = col[e + 3];
        unsigned u0 = *reinterpret_cast<const unsigned*>(xb + ((size_t)s0 << 7) + lane * 2);
        unsigned u1 = *reinterpret_cast<const unsigned*>(xb + ((size_t)s1 << 7) + lane * 2);
        unsigned u2 = *reinterpret_cast<const unsigned*>(xb + ((size_t)s2 << 7) + lane * 2);
        unsigned u3 = *reinterpret_cast<const unsigned*>(xb + ((size_t)s3 << 7) + lane * 2);
        a0x += __uint_as_float(u0 << 16); a0y += __uint_as_float(u0 & 0xFFFF0000u);
        a1x += __uint_as_float(u1 << 16); a1y += __uint_as_float(u1 & 0xFFFF0000u);
        a2x += __uint_as_float(u2 << 16); a2y += __uint_as_float(u2 & 0xFFFF0000u);
        a3x += __uint_as_float(u3 << 16); a3y += __uint_as_float(u3 & 0xFFFF0000u);
    }
    for (; e < end; ++e) {
        int s = col[e];
        unsigned u = *reinterpret_cast<const unsigned*>(xb + ((size_t)s << 7) + lane * 2);
        a0x += __uint_as_float(u << 16); a0y += __uint_as_float(u & 0xFFFF0000u);
    }
    float sx = (a0x + a1x) + (a2x + a3x);
    float sy = (a0y + a1y) + (a2y + a3y);
    int deg = end - beg;
    float inv = 1.0f / (float)(deg > 1 ? deg : 1);
    unsigned o = (unsigned)f2bf(sx * inv) | ((unsigned)f2bf(sy * inv) << 16);
    *reinterpret_cast<unsigned*>(mb + ((size_t)node << 7) + lane * 2) = o;
}

// ---------------- MFMA GEMM: out = act([mean||xin] @ [Wl;Wr] + b) [+ hres] ----------------
template<int FOUT, bool RELU, bool RES, bool OUTF>
__global__ __launch_bounds__(256) void mfma_gemm(
    const ushort* __restrict__ mb, const ushort* __restrict__ xin,
    const ushort* __restrict__ Wp, const float* __restrict__ bias,
    ushort* __restrict__ outb, float* __restrict__ outf,
    const ushort* __restrict__ hres, int N)
{
    constexpr int JT = FOUT / 16;
    __shared__ __align__(16) ushort sA[64 * 256];   // 64 rows x 32 slots(16B), XOR-swizzled
    const int tid = threadIdx.x;
    const int n0 = blockIdx.x * 64;

    for (int idx = tid; idx < 64 * 32; idx += 256) {
        int r = idx >> 5, s = idx & 31;
        int n = n0 + r; if (n >= N) n = N - 1;
        const uint4* src = (s < 16)
            ? reinterpret_cast<const uint4*>(mb  + ((size_t)n << 7) + (s << 3))
            : reinterpret_cast<const uint4*>(xin + ((size_t)n << 7) + ((s - 16) << 3));
        int sp = (s & 24) | ((s ^ r) & 7);
        *reinterpret_cast<uint4*>(&sA[(r << 8) + (sp << 3)]) = *src;
    }
    __syncthreads();

    const int lane = tid & 63;
    const int w = tid >> 6;
    const int rloc = w * 16 + (lane & 15);
    const int q = lane >> 4;

    f32x4 acc[JT];
#pragma unroll
    for (int jt = 0; jt < JT; ++jt) acc[jt] = (f32x4){0.f, 0.f, 0.f, 0.f};

#pragma unroll
    for (int kt = 0; kt < 8; ++kt) {
        int s = kt * 4 + q;
        int sp = (s & 24) | ((s ^ rloc) & 7);
        short8 a = *reinterpret_cast<const short8*>(&sA[(rloc << 8) + (sp << 3)]);
#pragma unroll
        for (int jt = 0; jt < JT; ++jt) {
            short8 b = *reinterpret_cast<const short8*>(Wp + ((size_t)((kt * JT + jt) * 64 + lane) << 3));
            acc[jt] = __builtin_amdgcn_mfma_f32_16x16x32_bf16(a, b, acc[jt], 0, 0, 0);
        }
    }

#pragma unroll
    for (int jt = 0; jt < JT; ++jt) {
        int j = jt * 16 + (lane & 15);
        float bj = bias[j];
#pragma unroll
        for (int reg = 0; reg < 4; ++reg) {
            int n = n0 + w * 16 + q * 4 + reg;
            if (n < N) {
                float v = acc[jt][reg] + bj;
                if (RELU) v = fmaxf(v, 0.f);
                if (RES)  v += bf2f(hres[((size_t)n << 7) + j]);
                if (OUTF) outf[(size_t)n * FOUT + j] = v;
                else      outb[(size_t)n * FOUT + j] = f2bf(v);
            }
        }
    }
}

extern "C" void kernel_launch(void* const* d_in, const int* in_sizes, int n_in,
                              void* d_out, int out_size, void* d_ws, size_t ws_size,
                              hipStream_t stream) {
    const float* x   = (const float*)d_in[0];
    const int*   ei1 = (const int*)d_in[1];
    const int*   ei2 = (const int*)d_in[2];
    const int*   ei3 = (const int*)d_in[3];
    const float* Wl1 = (const float*)d_in[4];
    const float* Wr1 = (const float*)d_in[5];
    const float* b1  = (const float*)d_in[6];
    const float* Wl2 = (const float*)d_in[7];
    const float* Wr2 = (const float*)d_in[8];
    const float* b2  = (const float*)d_in[9];
    const float* Wl3 = (const float*)d_in[10];
    const float* Wr3 = (const float*)d_in[11];
    const float* b3  = (const float*)d_in[12];
    float* out = (float*)d_out;

    const int N = in_sizes[0] / FDIM;   // 50000
    const int E = in_sizes[1] / 2;      // 800000
    const int NB = (N + 511) >> 9;      // 98 buckets of 512 nodes

    auto al = [](size_t v) { return (v + 255) & ~(size_t)255; };
    char* ws = (char*)d_ws;
    ushort* xb   = (ushort*)ws;   ws += al((size_t)N * FDIM * 2);
    ushort* hb   = (ushort*)ws;   ws += al((size_t)N * FDIM * 2);
    ushort* mb   = (ushort*)ws;   ws += al((size_t)N * FDIM * 2);
    ushort* Wp1  = (ushort*)ws;   ws += al((size_t)8 * 8 * 64 * 8 * 2);
    ushort* Wp2  = (ushort*)ws;   ws += al((size_t)8 * 8 * 64 * 8 * 2);
    ushort* Wp3  = (ushort*)ws;   ws += al((size_t)8 * 4 * 64 * 8 * 2);
    int*     rowptr = (int*)ws;   ws += al((size_t)(3 * N + 1) * 4);
    int*     gCnt   = (int*)ws;   ws += al((size_t)(3 * NB) * 4);
    unsigned* binned = (unsigned*)ws; ws += al((size_t)3 * NB * CAPB * 4);
    ushort*  colu   = (ushort*)ws;

    const int bpg = (E + 4095) / 4096;
    const int gatherBlocks = (N + 3) / 4;
    const int gemmBlocks   = (N + 63) / 64;

    // prep: bf16 features (+gCnt zero) + packed weights
    convert_kernel<<<(N * FDIM / 4 + 255) / 256, 256, 0, stream>>>(
        x, xb, N * FDIM / 4, gCnt, 3 * NB);
    pack3_kernel<<<40, 256, 0, stream>>>(Wl1, Wr1, Wl2, Wr2, Wl3, Wr3, Wp1, Wp2, Wp3);

    // CSR build for all 3 graphs: bin -> per-bucket fill (self-scanning)
    bin_kernel<<<3 * bpg, 256, 0, stream>>>(ei1, ei2, ei3, gCnt, binned, E, NB, bpg);
    fill2_kernel<<<3 * NB, 256, 0, stream>>>(binned, gCnt, rowptr, colu, N, NB);

    // layer 1: hb = relu(mean1@Wl1 + b1 + x@Wr1)
    gather_kernel<<<gatherBlocks, 256, 0, stream>>>(xb, rowptr, colu, mb, N);
    mfma_gemm<128, true, false, false><<<gemmBlocks, 256, 0, stream>>>(
        mb, xb, Wp1, b1, hb, nullptr, nullptr, N);

    // layer 2: hb = relu(mean2@Wl2 + b2 + hb@Wr2) + hb   (in-place: block owns its rows)
    gather_kernel<<<gatherBlocks, 256, 0, stream>>>(hb, rowptr + N, colu, mb, N);
    mfma_gemm<128, true, true, false><<<gemmBlocks, 256, 0, stream>>>(
        mb, hb, Wp2, b2, hb, nullptr, hb, N);

    // layer 3: out = mean3@Wl3 + b3 + hb@Wr3
    gather_kernel<<<gatherBlocks, 256, 0, stream>>>(hb, rowptr + 2 * N, colu, mb, N);
    mfma_gemm<64, false, false, true><<<gemmBlocks, 256, 0, stream>>>(
        mb, hb, Wp3, b3, nullptr, out, nullptr, N);
}

// Round 8
// 188.594 us; speedup vs baseline: 1.5771x; 1.1815x over previous
//
#include <hip/hip_runtime.h>

#define FDIM 128
#define NBMAX 128     // max dst-buckets per graph (N<=65536 -> <=128 buckets of 512)
#define CAPB 10240    // per-bucket capacity in binned[] (E/NB ~ 8163, 23 sigma slack)

typedef short short8 __attribute__((ext_vector_type(8)));
typedef float f32x4 __attribute__((ext_vector_type(4)));

static __device__ __forceinline__ unsigned short f2bf(float f) {
    unsigned u = __float_as_uint(f);
    u += 0x7FFF + ((u >> 16) & 1);          // round-to-nearest-even
    return (unsigned short)(u >> 16);
}
static __device__ __forceinline__ float bf2f(unsigned short h) {
    return __uint_as_float(((unsigned)h) << 16);
}

// ---------------- prep: pack weights (blocks 0..39) + fp32->bf16 convert + zero gCnt ----
__global__ __launch_bounds__(256) void prep_kernel(
    const float* __restrict__ x, ushort* __restrict__ xb, int n4,
    int* __restrict__ gCnt, int nb3,
    const float* __restrict__ Wl1, const float* __restrict__ Wr1,
    const float* __restrict__ Wl2, const float* __restrict__ Wr2,
    const float* __restrict__ Wl3, const float* __restrict__ Wr3,
    ushort* __restrict__ Wp1, ushort* __restrict__ Wp2, ushort* __restrict__ Wp3)
{
    int b = blockIdx.x;
    if (b < 40) {
        // pack all 3 layers' [Wl;Wr] into MFMA B-fragment order
        const float *Wl, *Wr; ushort* Wp; int FOUT, base;
        if (b < 16)      { Wl = Wl1; Wr = Wr1; Wp = Wp1; FOUT = 128; base = b; }
        else if (b < 32) { Wl = Wl2; Wr = Wr2; Wp = Wp2; FOUT = 128; base = b - 16; }
        else             { Wl = Wl3; Wr = Wr3; Wp = Wp3; FOUT = 64;  base = b - 32; }
        int JT = FOUT >> 4;
        int idx = base * 256 + threadIdx.x;
        if (idx >= 8 * JT * 64) return;
        int lane = idx & 63;
        int jt = (idx >> 6) % JT;
        int kt = (idx >> 6) / JT;
        int kbase = kt * 32 + (lane >> 4) * 8;
        int j = jt * 16 + (lane & 15);
        const float* W = (kbase < 128) ? Wl : Wr;
        int kb = kbase & 127;
        ushort tmp[8];
#pragma unroll
        for (int t = 0; t < 8; ++t) tmp[t] = f2bf(W[(size_t)(kb + t) * FOUT + j]);
        *reinterpret_cast<uint4*>(Wp + (size_t)idx * 8) = *reinterpret_cast<uint4*>(tmp);
        return;
    }
    int cb = b - 40;
    if (cb == 0) {
        for (int k = threadIdx.x; k < nb3; k += 256) gCnt[k] = 0;
    }
    int i = cb * 256 + threadIdx.x;
    if (i >= n4) return;
    float4 v = reinterpret_cast<const float4*>(x)[i];
    ushort4 o = { f2bf(v.x), f2bf(v.y), f2bf(v.z), f2bf(v.w) };
    reinterpret_cast<ushort4*>(xb)[i] = o;
}

// ---------------- pass 1: bin edges by dst bucket (counting sort in LDS) ----------------
// binned[(g*NB+b)*CAPB + k] = ((dst&511)<<16) | src   (requires N <= 65536)
__global__ __launch_bounds__(256) void bin_kernel(
    const int* __restrict__ ei1, const int* __restrict__ ei2, const int* __restrict__ ei3,
    int* __restrict__ gCnt, unsigned* __restrict__ binned,
    int E, int NB, int bpg)
{
    __shared__ int hist[NBMAX];
    __shared__ int excl[NBMAX];
    __shared__ int cursor[NBMAX];
    __shared__ int gbase[NBMAX];
    __shared__ unsigned stag[4096];
    __shared__ unsigned char sbk[4096];

    const int g = blockIdx.x / bpg;
    const int c = blockIdx.x % bpg;
    const int* ei = (g == 0) ? ei1 : (g == 1) ? ei2 : ei3;
    const int e0 = c * 4096;
    const int chunk = min(4096, E - e0);
    const int t = threadIdx.x;

    if (t < NB) hist[t] = 0;
    __syncthreads();
    for (int i = t; i < chunk; i += 256)
        atomicAdd(&hist[ei[E + e0 + i] >> 9], 1);
    __syncthreads();
    // exclusive scan over NB<=128 buckets: one wave, 2 adjacent elems per lane
    if (t < 64) {
        int a = (2 * t     < NB) ? hist[2 * t]     : 0;
        int b = (2 * t + 1 < NB) ? hist[2 * t + 1] : 0;
        int s = a + b, incl = s;
#pragma unroll
        for (int d = 1; d < 64; d <<= 1) {
            int x = __shfl_up(incl, d);
            if (t >= d) incl += x;
        }
        int ex = incl - s;
        if (2 * t     < NB) { excl[2 * t]     = ex;     cursor[2 * t]     = ex; }
        if (2 * t + 1 < NB) { excl[2 * t + 1] = ex + a; cursor[2 * t + 1] = ex + a; }
    }
    __syncthreads();
    if (t < NB) {
        int cnt = hist[t];
        gbase[t] = cnt ? atomicAdd(&gCnt[g * NB + t], cnt) : 0;
    }
    __syncthreads();
    // counting-sort the chunk into LDS (record bucket per slot)
    for (int i = t; i < chunk; i += 256) {
        int src = ei[e0 + i];
        int dst = ei[E + e0 + i];
        int bk = dst >> 9;
        int pl = atomicAdd(&cursor[bk], 1);
        stag[pl] = ((unsigned)(dst & 511) << 16) | (unsigned)src;
        sbk[pl] = (unsigned char)bk;
    }
    __syncthreads();
    // linear, run-contiguous writeback
    for (int i = t; i < chunk; i += 256) {
        int bk = sbk[i];
        int off = gbase[bk] + (i - excl[bk]);
        if (off < CAPB)
            binned[(size_t)(g * NB + bk) * CAPB + off] = stag[i];
    }
}

// ---------------- pass 2: per-bucket CSR fill (computes its own global scan) ----------------
__global__ __launch_bounds__(256) void fill2_kernel(
    const unsigned* __restrict__ binned, const int* __restrict__ gCnt,
    int* __restrict__ rowptr, ushort* __restrict__ colu, int N, int NB)
{
    __shared__ int hist[512];
    __shared__ int cursor[512];
    __shared__ int wsum[4];
    __shared__ int sColBase, sTotal;

    const int M = 3 * NB;
    const int gb = blockIdx.x;
    const int g = gb / NB, b = gb % NB;
    const int t = threadIdx.x;
    const int lane = t & 63, w = t >> 6;

    // inline exclusive scan of gCnt[0..M) to find this bucket's colBase
    {
        int v0 = (2 * t     < M) ? gCnt[2 * t]     : 0;
        int v1 = (2 * t + 1 < M) ? gCnt[2 * t + 1] : 0;
        int s2 = v0 + v1, incl = s2;
#pragma unroll
        for (int d = 1; d < 64; d <<= 1) {
            int x = __shfl_up(incl, d);
            if (lane >= d) incl += x;
        }
        if (lane == 63) wsum[w] = incl;
        __syncthreads();
        int woff = 0;
        for (int ww = 0; ww < w; ++ww) woff += wsum[ww];
        int ex = woff + incl - s2;            // exclusive prefix of elem 2t
        if (2 * t     == gb) sColBase = ex;
        if (2 * t + 1 == gb) sColBase = ex + v0;
        if (2 * t     == M - 1) sTotal = ex + v0;
        if (2 * t + 1 == M - 1) sTotal = ex + v0 + v1;
        __syncthreads();
    }
    const int colBase = sColBase;
    if (gb == 0 && t == 0) rowptr[(size_t)3 * N] = sTotal;

    const int n0 = b << 9;
    const int NL = min(512, N - n0);
    const int cnt = min(gCnt[gb], CAPB);
    const size_t ebase = (size_t)gb * CAPB;

    __syncthreads();
    hist[t] = 0; hist[t + 256] = 0;
    __syncthreads();
    for (int e = t; e < cnt; e += 256)
        atomicAdd(&hist[binned[ebase + e] >> 16], 1);
    __syncthreads();
    // scan 512 elems: 4 waves x (2 adjacent elems per lane)
    int a = hist[2 * t], bb = hist[2 * t + 1];
    int s2 = a + bb, incl = s2;
#pragma unroll
    for (int d = 1; d < 64; d <<= 1) {
        int x = __shfl_up(incl, d);
        if (lane >= d) incl += x;
    }
    if (lane == 63) wsum[w] = incl;
    __syncthreads();
    int woff = 0;
    for (int ww = 0; ww < w; ++ww) woff += wsum[ww];
    int ex = woff + incl - s2;                 // exclusive prefix for elem 2t
    if (2 * t     < NL) rowptr[(size_t)g * N + n0 + 2 * t]     = colBase + ex;
    if (2 * t + 1 < NL) rowptr[(size_t)g * N + n0 + 2 * t + 1] = colBase + ex + a;
    cursor[2 * t] = ex; cursor[2 * t + 1] = ex + a;
    __syncthreads();
    for (int e = t; e < cnt; e += 256) {
        unsigned u = binned[ebase + e];
        int pl = atomicAdd(&cursor[u >> 16], 1);
        colu[colBase + pl] = (ushort)(u & 0xFFFFu);
    }
}

// ---------------- gather (bf16): mean[n] = sum x[col[e]] / max(deg,1) ----------------
// 16 lanes per node, 16B (uint4 = 8 bf16) per lane, 4-edge unroll for MLP
__global__ __launch_bounds__(256) void gather_kernel(
    const ushort* __restrict__ xb, const int* __restrict__ rp,
    const ushort* __restrict__ col, ushort* __restrict__ mb, int N)
{
    int node = blockIdx.x * 16 + (threadIdx.x >> 4);
    if (node >= N) return;
    int l = threadIdx.x & 15;
    int beg = rp[node], end = rp[node + 1];
    float acc[8];
#pragma unroll
    for (int k = 0; k < 8; ++k) acc[k] = 0.f;

#define ACCUM(v)                                                            \
    acc[0] += __uint_as_float((v).x << 16); acc[1] += __uint_as_float((v).x & 0xFFFF0000u); \
    acc[2] += __uint_as_float((v).y << 16); acc[3] += __uint_as_float((v).y & 0xFFFF0000u); \
    acc[4] += __uint_as_float((v).z << 16); acc[5] += __uint_as_float((v).z & 0xFFFF0000u); \
    acc[6] += __uint_as_float((v).w << 16); acc[7] += __uint_as_float((v).w & 0xFFFF0000u);

    int e = beg;
    for (; e + 4 <= end; e += 4) {
        uint4 v0 = *reinterpret_cast<const uint4*>(xb + ((size_t)col[e]     << 7) + l * 8);
        uint4 v1 = *reinterpret_cast<const uint4*>(xb + ((size_t)col[e + 1] << 7) + l * 8);
        uint4 v2 = *reinterpret_cast<const uint4*>(xb + ((size_t)col[e + 2] << 7) + l * 8);
        uint4 v3 = *reinterpret_cast<const uint4*>(xb + ((size_t)col[e + 3] << 7) + l * 8);
        ACCUM(v0) ACCUM(v1) ACCUM(v2) ACCUM(v3)
    }
    for (; e < end; ++e) {
        uint4 v = *reinterpret_cast<const uint4*>(xb + ((size_t)col[e] << 7) + l * 8);
        ACCUM(v)
    }
#undef ACCUM

    int deg = end - beg;
    float inv = 1.0f / (float)(deg > 1 ? deg : 1);
    uint4 o;
    o.x = (unsigned)f2bf(acc[0] * inv) | ((unsigned)f2bf(acc[1] * inv) << 16);
    o.y = (unsigned)f2bf(acc[2] * inv) | ((unsigned)f2bf(acc[3] * inv) << 16);
    o.z = (unsigned)f2bf(acc[4] * inv) | ((unsigned)f2bf(acc[5] * inv) << 16);
    o.w = (unsigned)f2bf(acc[6] * inv) | ((unsigned)f2bf(acc[7] * inv) << 16);
    *reinterpret_cast<uint4*>(mb + ((size_t)node << 7) + l * 8) = o;
}

// ---------------- MFMA GEMM: out = act([mean||xin] @ [Wl;Wr] + b) [+ hres] ----------------
template<int FOUT, bool RELU, bool RES, bool OUTF>
__global__ __launch_bounds__(256) void mfma_gemm(
    const ushort* __restrict__ mb, const ushort* __restrict__ xin,
    const ushort* __restrict__ Wp, const float* __restrict__ bias,
    ushort* __restrict__ outb, float* __restrict__ outf,
    const ushort* __restrict__ hres, int N)
{
    constexpr int JT = FOUT / 16;
    __shared__ __align__(16) ushort sA[64 * 256];   // 64 rows x 32 slots(16B), XOR-swizzled
    const int tid = threadIdx.x;
    const int n0 = blockIdx.x * 64;

    for (int idx = tid; idx < 64 * 32; idx += 256) {
        int r = idx >> 5, s = idx & 31;
        int n = n0 + r; if (n >= N) n = N - 1;
        const uint4* src = (s < 16)
            ? reinterpret_cast<const uint4*>(mb  + ((size_t)n << 7) + (s << 3))
            : reinterpret_cast<const uint4*>(xin + ((size_t)n << 7) + ((s - 16) << 3));
        int sp = (s & 24) | ((s ^ r) & 7);
        *reinterpret_cast<uint4*>(&sA[(r << 8) + (sp << 3)]) = *src;
    }
    __syncthreads();

    const int lane = tid & 63;
    const int w = tid >> 6;
    const int rloc = w * 16 + (lane & 15);
    const int q = lane >> 4;

    f32x4 acc[JT];
#pragma unroll
    for (int jt = 0; jt < JT; ++jt) acc[jt] = (f32x4){0.f, 0.f, 0.f, 0.f};

#pragma unroll
    for (int kt = 0; kt < 8; ++kt) {
        int s = kt * 4 + q;
        int sp = (s & 24) | ((s ^ rloc) & 7);
        short8 a = *reinterpret_cast<const short8*>(&sA[(rloc << 8) + (sp << 3)]);
#pragma unroll
        for (int jt = 0; jt < JT; ++jt) {
            short8 b = *reinterpret_cast<const short8*>(Wp + ((size_t)((kt * JT + jt) * 64 + lane) << 3));
            acc[jt] = __builtin_amdgcn_mfma_f32_16x16x32_bf16(a, b, acc[jt], 0, 0, 0);
        }
    }

#pragma unroll
    for (int jt = 0; jt < JT; ++jt) {
        int j = jt * 16 + (lane & 15);
        float bj = bias[j];
#pragma unroll
        for (int reg = 0; reg < 4; ++reg) {
            int n = n0 + w * 16 + q * 4 + reg;
            if (n < N) {
                float v = acc[jt][reg] + bj;
                if (RELU) v = fmaxf(v, 0.f);
                if (RES)  v += bf2f(hres[((size_t)n << 7) + j]);
                if (OUTF) outf[(size_t)n * FOUT + j] = v;
                else      outb[(size_t)n * FOUT + j] = f2bf(v);
            }
        }
    }
}

extern "C" void kernel_launch(void* const* d_in, const int* in_sizes, int n_in,
                              void* d_out, int out_size, void* d_ws, size_t ws_size,
                              hipStream_t stream) {
    const float* x   = (const float*)d_in[0];
    const int*   ei1 = (const int*)d_in[1];
    const int*   ei2 = (const int*)d_in[2];
    const int*   ei3 = (const int*)d_in[3];
    const float* Wl1 = (const float*)d_in[4];
    const float* Wr1 = (const float*)d_in[5];
    const float* b1  = (const float*)d_in[6];
    const float* Wl2 = (const float*)d_in[7];
    const float* Wr2 = (const float*)d_in[8];
    const float* b2  = (const float*)d_in[9];
    const float* Wl3 = (const float*)d_in[10];
    const float* Wr3 = (const float*)d_in[11];
    const float* b3  = (const float*)d_in[12];
    float* out = (float*)d_out;

    const int N = in_sizes[0] / FDIM;   // 50000
    const int E = in_sizes[1] / 2;      // 800000
    const int NB = (N + 511) >> 9;      // 98 buckets of 512 nodes

    auto al = [](size_t v) { return (v + 255) & ~(size_t)255; };
    char* ws = (char*)d_ws;
    ushort* xb   = (ushort*)ws;   ws += al((size_t)N * FDIM * 2);
    ushort* hb   = (ushort*)ws;   ws += al((size_t)N * FDIM * 2);
    ushort* mb   = (ushort*)ws;   ws += al((size_t)N * FDIM * 2);
    ushort* Wp1  = (ushort*)ws;   ws += al((size_t)8 * 8 * 64 * 8 * 2);
    ushort* Wp2  = (ushort*)ws;   ws += al((size_t)8 * 8 * 64 * 8 * 2);
    ushort* Wp3  = (ushort*)ws;   ws += al((size_t)8 * 4 * 64 * 8 * 2);
    int*     rowptr = (int*)ws;   ws += al((size_t)(3 * N + 1) * 4);
    int*     gCnt   = (int*)ws;   ws += al((size_t)(3 * NB) * 4);
    unsigned* binned = (unsigned*)ws; ws += al((size_t)3 * NB * CAPB * 4);
    ushort*  colu   = (ushort*)ws;

    const int bpg = (E + 4095) / 4096;
    const int n4  = N * FDIM / 4;
    const int gatherBlocks = (N + 15) / 16;
    const int gemmBlocks   = (N + 63) / 64;

    // prep: weight pack (40 blocks) + bf16 convert (+gCnt zero)
    prep_kernel<<<40 + (n4 + 255) / 256, 256, 0, stream>>>(
        x, xb, n4, gCnt, 3 * NB, Wl1, Wr1, Wl2, Wr2, Wl3, Wr3, Wp1, Wp2, Wp3);

    // CSR build for all 3 graphs: bin -> per-bucket fill (self-scanning)
    bin_kernel<<<3 * bpg, 256, 0, stream>>>(ei1, ei2, ei3, gCnt, binned, E, NB, bpg);
    fill2_kernel<<<3 * NB, 256, 0, stream>>>(binned, gCnt, rowptr, colu, N, NB);

    // layer 1: hb = relu(mean1@Wl1 + b1 + x@Wr1)
    gather_kernel<<<gatherBlocks, 256, 0, stream>>>(xb, rowptr, colu, mb, N);
    mfma_gemm<128, true, false, false><<<gemmBlocks, 256, 0, stream>>>(
        mb, xb, Wp1, b1, hb, nullptr, nullptr, N);

    // layer 2: hb = relu(mean2@Wl2 + b2 + hb@Wr2) + hb   (in-place: block owns its rows)
    gather_kernel<<<gatherBlocks, 256, 0, stream>>>(hb, rowptr + N, colu, mb, N);
    mfma_gemm<128, true, true, false><<<gemmBlocks, 256, 0, stream>>>(
        mb, hb, Wp2, b2, hb, nullptr, hb, N);

    // layer 3: out = mean3@Wl3 + b3 + hb@Wr3
    gather_kernel<<<gatherBlocks, 256, 0, stream>>>(hb, rowptr + 2 * N, colu, mb, N);
    mfma_gemm<64, false, false, true><<<gemmBlocks, 256, 0, stream>>>(
        mb, hb, Wp3, b3, nullptr, out, nullptr, N);
}

// Round 9
// 181.369 us; speedup vs baseline: 1.6399x; 1.0398x over previous
//
#include <hip/hip_runtime.h>

#define FDIM 128
#define NBMAX 128     // max dst-buckets per graph (N<=65536 -> <=128 buckets of 512)
#define CAPB 10240    // per-bucket capacity in binned[] (E/NB ~ 8163, 23 sigma slack)

typedef short short8 __attribute__((ext_vector_type(8)));
typedef float f32x4 __attribute__((ext_vector_type(4)));

static __device__ __forceinline__ unsigned short f2bf(float f) {
    unsigned u = __float_as_uint(f);
    u += 0x7FFF + ((u >> 16) & 1);          // round-to-nearest-even
    return (unsigned short)(u >> 16);
}
static __device__ __forceinline__ float bf2f(unsigned short h) {
    return __uint_as_float(((unsigned)h) << 16);
}

// ---------------- prep: pack weights (blocks 0..39) + fp32->bf16 convert + zero gCnt ----
// Wp1/Wp2: [Wl;Wr] stacked over K=256, FOUT=128. Wp3: [Wl3 | Wr3] side-by-side, K=128, FOUT=128.
__global__ __launch_bounds__(256) void prep_kernel(
    const float* __restrict__ x, ushort* __restrict__ xb, int n4,
    int* __restrict__ gCnt, int nb3,
    const float* __restrict__ Wl1, const float* __restrict__ Wr1,
    const float* __restrict__ Wl2, const float* __restrict__ Wr2,
    const float* __restrict__ Wl3, const float* __restrict__ Wr3,
    ushort* __restrict__ Wp1, ushort* __restrict__ Wp2, ushort* __restrict__ Wp3)
{
    int b = blockIdx.x;
    if (b < 32) {
        // layers 1-2: K=256 ([Wl;Wr] stacked), FOUT=128
        const float *Wl, *Wr; ushort* Wp; int base;
        if (b < 16) { Wl = Wl1; Wr = Wr1; Wp = Wp1; base = b; }
        else        { Wl = Wl2; Wr = Wr2; Wp = Wp2; base = b - 16; }
        int idx = base * 256 + threadIdx.x;          // < 8*8*64 = 4096
        int lane = idx & 63;
        int jt = (idx >> 6) % 8;
        int kt = (idx >> 6) / 8;
        int kbase = kt * 32 + (lane >> 4) * 8;
        int j = jt * 16 + (lane & 15);
        const float* W = (kbase < 128) ? Wl : Wr;
        int kb = kbase & 127;
        ushort tmp[8];
#pragma unroll
        for (int t = 0; t < 8; ++t) tmp[t] = f2bf(W[(size_t)(kb + t) * 128 + j]);
        *reinterpret_cast<uint4*>(Wp + (size_t)idx * 8) = *reinterpret_cast<uint4*>(tmp);
        return;
    }
    if (b < 40) {
        // layer 3: K=128, FOUT=128 = [Wl3 (64 cols) | Wr3 (64 cols)]
        int idx = (b - 32) * 256 + threadIdx.x;      // < 4*8*64 = 2048
        if (idx >= 4 * 8 * 64) return;
        int lane = idx & 63;
        int jt = (idx >> 6) % 8;
        int kt = (idx >> 6) / 8;                     // 0..3
        int kbase = kt * 32 + (lane >> 4) * 8;
        int j = jt * 16 + (lane & 15);
        const float* W = (j < 64) ? Wl3 : Wr3;
        int jj = j & 63;
        ushort tmp[8];
#pragma unroll
        for (int t = 0; t < 8; ++t) tmp[t] = f2bf(W[(size_t)(kbase + t) * 64 + jj]);
        *reinterpret_cast<uint4*>(Wp3 + (size_t)idx * 8) = *reinterpret_cast<uint4*>(tmp);
        return;
    }
    int cb = b - 40;
    if (cb == 0) {
        for (int k = threadIdx.x; k < nb3; k += 256) gCnt[k] = 0;
    }
    int i = cb * 256 + threadIdx.x;
    if (i >= n4) return;
    float4 v = reinterpret_cast<const float4*>(x)[i];
    ushort4 o = { f2bf(v.x), f2bf(v.y), f2bf(v.z), f2bf(v.w) };
    reinterpret_cast<ushort4*>(xb)[i] = o;
}

// ---------------- pass 1: bin edges by dst bucket (counting sort in LDS) ----------------
// binned[(g*NB+b)*CAPB + k] = ((dst&511)<<16) | src   (requires N <= 65536)
__global__ __launch_bounds__(256) void bin_kernel(
    const int* __restrict__ ei1, const int* __restrict__ ei2, const int* __restrict__ ei3,
    int* __restrict__ gCnt, unsigned* __restrict__ binned,
    int E, int NB, int bpg)
{
    __shared__ int hist[NBMAX];
    __shared__ int excl[NBMAX];
    __shared__ int cursor[NBMAX];
    __shared__ int gbase[NBMAX];
    __shared__ unsigned stag[4096];
    __shared__ unsigned char sbk[4096];

    const int g = blockIdx.x / bpg;
    const int c = blockIdx.x % bpg;
    const int* ei = (g == 0) ? ei1 : (g == 1) ? ei2 : ei3;
    const int e0 = c * 4096;
    const int chunk = min(4096, E - e0);
    const int t = threadIdx.x;

    if (t < NB) hist[t] = 0;
    __syncthreads();
    for (int i = t; i < chunk; i += 256)
        atomicAdd(&hist[ei[E + e0 + i] >> 9], 1);
    __syncthreads();
    if (t < 64) {
        int a = (2 * t     < NB) ? hist[2 * t]     : 0;
        int b = (2 * t + 1 < NB) ? hist[2 * t + 1] : 0;
        int s = a + b, incl = s;
#pragma unroll
        for (int d = 1; d < 64; d <<= 1) {
            int x = __shfl_up(incl, d);
            if (t >= d) incl += x;
        }
        int ex = incl - s;
        if (2 * t     < NB) { excl[2 * t]     = ex;     cursor[2 * t]     = ex; }
        if (2 * t + 1 < NB) { excl[2 * t + 1] = ex + a; cursor[2 * t + 1] = ex + a; }
    }
    __syncthreads();
    if (t < NB) {
        int cnt = hist[t];
        gbase[t] = cnt ? atomicAdd(&gCnt[g * NB + t], cnt) : 0;
    }
    __syncthreads();
    for (int i = t; i < chunk; i += 256) {
        int src = ei[e0 + i];
        int dst = ei[E + e0 + i];
        int bk = dst >> 9;
        int pl = atomicAdd(&cursor[bk], 1);
        stag[pl] = ((unsigned)(dst & 511) << 16) | (unsigned)src;
        sbk[pl] = (unsigned char)bk;
    }
    __syncthreads();
    for (int i = t; i < chunk; i += 256) {
        int bk = sbk[i];
        int off = gbase[bk] + (i - excl[bk]);
        if (off < CAPB)
            binned[(size_t)(g * NB + bk) * CAPB + off] = stag[i];
    }
}

// ---------------- pass 2: per-bucket CSR fill (computes its own global scan) ----------------
__global__ __launch_bounds__(256) void fill2_kernel(
    const unsigned* __restrict__ binned, const int* __restrict__ gCnt,
    int* __restrict__ rowptr, ushort* __restrict__ colu, int N, int NB)
{
    __shared__ int hist[512];
    __shared__ int cursor[512];
    __shared__ int wsum[4];
    __shared__ int sColBase, sTotal;

    const int M = 3 * NB;
    const int gb = blockIdx.x;
    const int g = gb / NB, b = gb % NB;
    const int t = threadIdx.x;
    const int lane = t & 63, w = t >> 6;

    {
        int v0 = (2 * t     < M) ? gCnt[2 * t]     : 0;
        int v1 = (2 * t + 1 < M) ? gCnt[2 * t + 1] : 0;
        int s2 = v0 + v1, incl = s2;
#pragma unroll
        for (int d = 1; d < 64; d <<= 1) {
            int x = __shfl_up(incl, d);
            if (lane >= d) incl += x;
        }
        if (lane == 63) wsum[w] = incl;
        __syncthreads();
        int woff = 0;
        for (int ww = 0; ww < w; ++ww) woff += wsum[ww];
        int ex = woff + incl - s2;
        if (2 * t     == gb) sColBase = ex;
        if (2 * t + 1 == gb) sColBase = ex + v0;
        if (2 * t     == M - 1) sTotal = ex + v0;
        if (2 * t + 1 == M - 1) sTotal = ex + v0 + v1;
        __syncthreads();
    }
    const int colBase = sColBase;
    if (gb == 0 && t == 0) rowptr[(size_t)3 * N] = sTotal;

    const int n0 = b << 9;
    const int NL = min(512, N - n0);
    const int cnt = min(gCnt[gb], CAPB);
    const size_t ebase = (size_t)gb * CAPB;

    __syncthreads();
    hist[t] = 0; hist[t + 256] = 0;
    __syncthreads();
    for (int e = t; e < cnt; e += 256)
        atomicAdd(&hist[binned[ebase + e] >> 16], 1);
    __syncthreads();
    int a = hist[2 * t], bb = hist[2 * t + 1];
    int s2 = a + bb, incl = s2;
#pragma unroll
    for (int d = 1; d < 64; d <<= 1) {
        int x = __shfl_up(incl, d);
        if (lane >= d) incl += x;
    }
    if (lane == 63) wsum[w] = incl;
    __syncthreads();
    int woff = 0;
    for (int ww = 0; ww < w; ++ww) woff += wsum[ww];
    int ex = woff + incl - s2;
    if (2 * t     < NL) rowptr[(size_t)g * N + n0 + 2 * t]     = colBase + ex;
    if (2 * t + 1 < NL) rowptr[(size_t)g * N + n0 + 2 * t + 1] = colBase + ex + a;
    cursor[2 * t] = ex; cursor[2 * t + 1] = ex + a;
    __syncthreads();
    for (int e = t; e < cnt; e += 256) {
        unsigned u = binned[ebase + e];
        int pl = atomicAdd(&cursor[u >> 16], 1);
        colu[colBase + pl] = (ushort)(u & 0xFFFFu);
    }
}

#define ACCUM(v)                                                            \
    acc[0] += __uint_as_float((v).x << 16); acc[1] += __uint_as_float((v).x & 0xFFFF0000u); \
    acc[2] += __uint_as_float((v).y << 16); acc[3] += __uint_as_float((v).y & 0xFFFF0000u); \
    acc[4] += __uint_as_float((v).z << 16); acc[5] += __uint_as_float((v).z & 0xFFFF0000u); \
    acc[6] += __uint_as_float((v).w << 16); acc[7] += __uint_as_float((v).w & 0xFFFF0000u);

// ---------------- gather (bf16, 128-wide rows): mean[n] = sum x[col[e]] / max(deg,1) ----
// 16 lanes per node, 16B per lane, 8-edge unroll
__global__ __launch_bounds__(256) void gather_kernel(
    const ushort* __restrict__ xb, const int* __restrict__ rp,
    const ushort* __restrict__ col, ushort* __restrict__ mb, int N)
{
    int node = blockIdx.x * 16 + (threadIdx.x >> 4);
    if (node >= N) return;
    int l = threadIdx.x & 15;
    int beg = rp[node], end = rp[node + 1];
    float acc[8];
#pragma unroll
    for (int k = 0; k < 8; ++k) acc[k] = 0.f;

    int e = beg;
    for (; e + 8 <= end; e += 8) {
        uint4 v0 = *reinterpret_cast<const uint4*>(xb + ((size_t)col[e]     << 7) + l * 8);
        uint4 v1 = *reinterpret_cast<const uint4*>(xb + ((size_t)col[e + 1] << 7) + l * 8);
        uint4 v2 = *reinterpret_cast<const uint4*>(xb + ((size_t)col[e + 2] << 7) + l * 8);
        uint4 v3 = *reinterpret_cast<const uint4*>(xb + ((size_t)col[e + 3] << 7) + l * 8);
        uint4 v4 = *reinterpret_cast<const uint4*>(xb + ((size_t)col[e + 4] << 7) + l * 8);
        uint4 v5 = *reinterpret_cast<const uint4*>(xb + ((size_t)col[e + 5] << 7) + l * 8);
        uint4 v6 = *reinterpret_cast<const uint4*>(xb + ((size_t)col[e + 6] << 7) + l * 8);
        uint4 v7 = *reinterpret_cast<const uint4*>(xb + ((size_t)col[e + 7] << 7) + l * 8);
        ACCUM(v0) ACCUM(v1) ACCUM(v2) ACCUM(v3)
        ACCUM(v4) ACCUM(v5) ACCUM(v6) ACCUM(v7)
    }
    for (; e + 4 <= end; e += 4) {
        uint4 v0 = *reinterpret_cast<const uint4*>(xb + ((size_t)col[e]     << 7) + l * 8);
        uint4 v1 = *reinterpret_cast<const uint4*>(xb + ((size_t)col[e + 1] << 7) + l * 8);
        uint4 v2 = *reinterpret_cast<const uint4*>(xb + ((size_t)col[e + 2] << 7) + l * 8);
        uint4 v3 = *reinterpret_cast<const uint4*>(xb + ((size_t)col[e + 3] << 7) + l * 8);
        ACCUM(v0) ACCUM(v1) ACCUM(v2) ACCUM(v3)
    }
    for (; e < end; ++e) {
        uint4 v = *reinterpret_cast<const uint4*>(xb + ((size_t)col[e] << 7) + l * 8);
        ACCUM(v)
    }

    int deg = end - beg;
    float inv = 1.0f / (float)(deg > 1 ? deg : 1);
    uint4 o;
    o.x = (unsigned)f2bf(acc[0] * inv) | ((unsigned)f2bf(acc[1] * inv) << 16);
    o.y = (unsigned)f2bf(acc[2] * inv) | ((unsigned)f2bf(acc[3] * inv) << 16);
    o.z = (unsigned)f2bf(acc[4] * inv) | ((unsigned)f2bf(acc[5] * inv) << 16);
    o.w = (unsigned)f2bf(acc[6] * inv) | ((unsigned)f2bf(acc[7] * inv) << 16);
    *reinterpret_cast<uint4*>(mb + ((size_t)node << 7) + l * 8) = o;
}

// ---------------- gather3: out[n] += mean over edges of y3[col[e]] (64-wide rows) ----
// 8 lanes per node, 16B per lane, 8-edge unroll; out already holds h@Wr3 + b3
__global__ __launch_bounds__(256) void gather3_kernel(
    const ushort* __restrict__ y3, const int* __restrict__ rp,
    const ushort* __restrict__ col, float* __restrict__ out, int N)
{
    int node = blockIdx.x * 32 + (threadIdx.x >> 3);
    if (node >= N) return;
    int l = threadIdx.x & 7;
    int beg = rp[node], end = rp[node + 1];
    float acc[8];
#pragma unroll
    for (int k = 0; k < 8; ++k) acc[k] = 0.f;

    int e = beg;
    for (; e + 8 <= end; e += 8) {
        uint4 v0 = *reinterpret_cast<const uint4*>(y3 + ((size_t)col[e]     << 6) + l * 8);
        uint4 v1 = *reinterpret_cast<const uint4*>(y3 + ((size_t)col[e + 1] << 6) + l * 8);
        uint4 v2 = *reinterpret_cast<const uint4*>(y3 + ((size_t)col[e + 2] << 6) + l * 8);
        uint4 v3 = *reinterpret_cast<const uint4*>(y3 + ((size_t)col[e + 3] << 6) + l * 8);
        uint4 v4 = *reinterpret_cast<const uint4*>(y3 + ((size_t)col[e + 4] << 6) + l * 8);
        uint4 v5 = *reinterpret_cast<const uint4*>(y3 + ((size_t)col[e + 5] << 6) + l * 8);
        uint4 v6 = *reinterpret_cast<const uint4*>(y3 + ((size_t)col[e + 6] << 6) + l * 8);
        uint4 v7 = *reinterpret_cast<const uint4*>(y3 + ((size_t)col[e + 7] << 6) + l * 8);
        ACCUM(v0) ACCUM(v1) ACCUM(v2) ACCUM(v3)
        ACCUM(v4) ACCUM(v5) ACCUM(v6) ACCUM(v7)
    }
    for (; e + 4 <= end; e += 4) {
        uint4 v0 = *reinterpret_cast<const uint4*>(y3 + ((size_t)col[e]     << 6) + l * 8);
        uint4 v1 = *reinterpret_cast<const uint4*>(y3 + ((size_t)col[e + 1] << 6) + l * 8);
        uint4 v2 = *reinterpret_cast<const uint4*>(y3 + ((size_t)col[e + 2] << 6) + l * 8);
        uint4 v3 = *reinterpret_cast<const uint4*>(y3 + ((size_t)col[e + 3] << 6) + l * 8);
        ACCUM(v0) ACCUM(v1) ACCUM(v2) ACCUM(v3)
    }
    for (; e < end; ++e) {
        uint4 v = *reinterpret_cast<const uint4*>(y3 + ((size_t)col[e] << 6) + l * 8);
        ACCUM(v)
    }

    int deg = end - beg;
    float inv = 1.0f / (float)(deg > 1 ? deg : 1);
    float* po = out + ((size_t)node << 6) + l * 8;
    float4 o0 = *reinterpret_cast<const float4*>(po);
    float4 o1 = *reinterpret_cast<const float4*>(po + 4);
    o0.x += acc[0] * inv; o0.y += acc[1] * inv; o0.z += acc[2] * inv; o0.w += acc[3] * inv;
    o1.x += acc[4] * inv; o1.y += acc[5] * inv; o1.z += acc[6] * inv; o1.w += acc[7] * inv;
    *reinterpret_cast<float4*>(po)     = o0;
    *reinterpret_cast<float4*>(po + 4) = o1;
}
#undef ACCUM

// ---------------- MFMA GEMM (layers 1-2): out = act([mean||xin]@[Wl;Wr] + b) [+ hres] ----
template<bool RES>
__global__ __launch_bounds__(256) void mfma_gemm(
    const ushort* __restrict__ mb, const ushort* __restrict__ xin,
    const ushort* __restrict__ Wp, const float* __restrict__ bias,
    ushort* __restrict__ outb, const ushort* __restrict__ hres, int N)
{
    __shared__ __align__(16) ushort sA[64 * 256];   // 64 rows x 32 slots(16B), XOR-swizzled
    const int tid = threadIdx.x;
    const int n0 = blockIdx.x * 64;

    for (int idx = tid; idx < 64 * 32; idx += 256) {
        int r = idx >> 5, s = idx & 31;
        int n = n0 + r; if (n >= N) n = N - 1;
        const uint4* src = (s < 16)
            ? reinterpret_cast<const uint4*>(mb  + ((size_t)n << 7) + (s << 3))
            : reinterpret_cast<const uint4*>(xin + ((size_t)n << 7) + ((s - 16) << 3));
        int sp = (s & 24) | ((s ^ r) & 7);
        *reinterpret_cast<uint4*>(&sA[(r << 8) + (sp << 3)]) = *src;
    }
    __syncthreads();

    const int lane = tid & 63;
    const int w = tid >> 6;
    const int rloc = w * 16 + (lane & 15);
    const int q = lane >> 4;

    f32x4 acc[8];
#pragma unroll
    for (int jt = 0; jt < 8; ++jt) acc[jt] = (f32x4){0.f, 0.f, 0.f, 0.f};

#pragma unroll
    for (int kt = 0; kt < 8; ++kt) {
        int s = kt * 4 + q;
        int sp = (s & 24) | ((s ^ rloc) & 7);
        short8 a = *reinterpret_cast<const short8*>(&sA[(rloc << 8) + (sp << 3)]);
#pragma unroll
        for (int jt = 0; jt < 8; ++jt) {
            short8 b = *reinterpret_cast<const short8*>(Wp + ((size_t)((kt * 8 + jt) * 64 + lane) << 3));
            acc[jt] = __builtin_amdgcn_mfma_f32_16x16x32_bf16(a, b, acc[jt], 0, 0, 0);
        }
    }

#pragma unroll
    for (int jt = 0; jt < 8; ++jt) {
        int j = jt * 16 + (lane & 15);
        float bj = bias[j];
#pragma unroll
        for (int reg = 0; reg < 4; ++reg) {
            int n = n0 + w * 16 + q * 4 + reg;
            if (n < N) {
                float v = fmaxf(acc[jt][reg] + bj, 0.f);
                if (RES) v += bf2f(hres[((size_t)n << 7) + j]);
                outb[((size_t)n << 7) + j] = f2bf(v);
            }
        }
    }
}

// ---------------- MFMA GEMM layer 3: [y3|z3] = h @ [Wl3|Wr3]; y3->bf16, z3+b3->out ----
__global__ __launch_bounds__(256) void mfma_gemm3(
    const ushort* __restrict__ h, const ushort* __restrict__ Wp,
    const float* __restrict__ bias, ushort* __restrict__ y3,
    float* __restrict__ out, int N)
{
    __shared__ __align__(16) ushort sA[64 * 128];   // 64 rows x 16 slots(16B), XOR-swizzled
    const int tid = threadIdx.x;
    const int n0 = blockIdx.x * 64;

    for (int idx = tid; idx < 64 * 16; idx += 256) {
        int r = idx >> 4, s = idx & 15;
        int n = n0 + r; if (n >= N) n = N - 1;
        uint4 v = *reinterpret_cast<const uint4*>(h + ((size_t)n << 7) + (s << 3));
        int sp = (s & 8) | ((s ^ r) & 7);
        *reinterpret_cast<uint4*>(&sA[(r << 7) + (sp << 3)]) = v;
    }
    __syncthreads();

    const int lane = tid & 63;
    const int w = tid >> 6;
    const int rloc = w * 16 + (lane & 15);
    const int q = lane >> 4;

    f32x4 acc[8];
#pragma unroll
    for (int jt = 0; jt < 8; ++jt) acc[jt] = (f32x4){0.f, 0.f, 0.f, 0.f};

#pragma unroll
    for (int kt = 0; kt < 4; ++kt) {
        int s = kt * 4 + q;
        int sp = (s & 8) | ((s ^ rloc) & 7);
        short8 a = *reinterpret_cast<const short8*>(&sA[(rloc << 7) + (sp << 3)]);
#pragma unroll
        for (int jt = 0; jt < 8; ++jt) {
            short8 b = *reinterpret_cast<const short8*>(Wp + ((size_t)((kt * 8 + jt) * 64 + lane) << 3));
            acc[jt] = __builtin_amdgcn_mfma_f32_16x16x32_bf16(a, b, acc[jt], 0, 0, 0);
        }
    }

#pragma unroll
    for (int jt = 0; jt < 8; ++jt) {
        int j = jt * 16 + (lane & 15);
#pragma unroll
        for (int reg = 0; reg < 4; ++reg) {
            int n = n0 + w * 16 + q * 4 + reg;
            if (n < N) {
                if (jt < 4) {
                    y3[((size_t)n << 6) + j] = f2bf(acc[jt][reg]);
                } else {
                    out[((size_t)n << 6) + (j - 64)] = acc[jt][reg] + bias[j - 64];
                }
            }
        }
    }
}

extern "C" void kernel_launch(void* const* d_in, const int* in_sizes, int n_in,
                              void* d_out, int out_size, void* d_ws, size_t ws_size,
                              hipStream_t stream) {
    const float* x   = (const float*)d_in[0];
    const int*   ei1 = (const int*)d_in[1];
    const int*   ei2 = (const int*)d_in[2];
    const int*   ei3 = (const int*)d_in[3];
    const float* Wl1 = (const float*)d_in[4];
    const float* Wr1 = (const float*)d_in[5];
    const float* b1  = (const float*)d_in[6];
    const float* Wl2 = (const float*)d_in[7];
    const float* Wr2 = (const float*)d_in[8];
    const float* b2  = (const float*)d_in[9];
    const float* Wl3 = (const float*)d_in[10];
    const float* Wr3 = (const float*)d_in[11];
    const float* b3  = (const float*)d_in[12];
    float* out = (float*)d_out;

    const int N = in_sizes[0] / FDIM;   // 50000
    const int E = in_sizes[1] / 2;      // 800000
    const int NB = (N + 511) >> 9;      // 98 buckets of 512 nodes

    auto al = [](size_t v) { return (v + 255) & ~(size_t)255; };
    char* ws = (char*)d_ws;
    ushort* xb   = (ushort*)ws;   ws += al((size_t)N * FDIM * 2);
    ushort* hb   = (ushort*)ws;   ws += al((size_t)N * FDIM * 2);
    ushort* mb   = (ushort*)ws;   ws += al((size_t)N * FDIM * 2);   // also y3 (N x 64)
    ushort* Wp1  = (ushort*)ws;   ws += al((size_t)8 * 8 * 64 * 8 * 2);
    ushort* Wp2  = (ushort*)ws;   ws += al((size_t)8 * 8 * 64 * 8 * 2);
    ushort* Wp3  = (ushort*)ws;   ws += al((size_t)4 * 8 * 64 * 8 * 2);
    int*     rowptr = (int*)ws;   ws += al((size_t)(3 * N + 1) * 4);
    int*     gCnt   = (int*)ws;   ws += al((size_t)(3 * NB) * 4);
    unsigned* binned = (unsigned*)ws; ws += al((size_t)3 * NB * CAPB * 4);
    ushort*  colu   = (ushort*)ws;

    const int bpg = (E + 4095) / 4096;
    const int n4  = N * FDIM / 4;
    const int gatherBlocks  = (N + 15) / 16;
    const int gather3Blocks = (N + 31) / 32;
    const int gemmBlocks    = (N + 63) / 64;

    // prep: weight pack (40 blocks) + bf16 convert (+gCnt zero)
    prep_kernel<<<40 + (n4 + 255) / 256, 256, 0, stream>>>(
        x, xb, n4, gCnt, 3 * NB, Wl1, Wr1, Wl2, Wr2, Wl3, Wr3, Wp1, Wp2, Wp3);

    // CSR build for all 3 graphs: bin -> per-bucket fill (self-scanning)
    bin_kernel<<<3 * bpg, 256, 0, stream>>>(ei1, ei2, ei3, gCnt, binned, E, NB, bpg);
    fill2_kernel<<<3 * NB, 256, 0, stream>>>(binned, gCnt, rowptr, colu, N, NB);

    // layer 1: hb = relu(mean1@Wl1 + b1 + x@Wr1)
    gather_kernel<<<gatherBlocks, 256, 0, stream>>>(xb, rowptr, colu, mb, N);
    mfma_gemm<false><<<gemmBlocks, 256, 0, stream>>>(
        mb, xb, Wp1, b1, hb, nullptr, N);

    // layer 2: hb = relu(mean2@Wl2 + b2 + hb@Wr2) + hb   (in-place: block owns its rows)
    gather_kernel<<<gatherBlocks, 256, 0, stream>>>(hb, rowptr + N, colu, mb, N);
    mfma_gemm<true><<<gemmBlocks, 256, 0, stream>>>(
        mb, hb, Wp2, b2, hb, hb, N);

    // layer 3: [y3|z3] = hb @ [Wl3|Wr3]; out = z3 + b3, then out += mean3(y3)
    mfma_gemm3<<<gemmBlocks, 256, 0, stream>>>(hb, Wp3, b3, mb, out, N);
    gather3_kernel<<<gather3Blocks, 256, 0, stream>>>(mb, rowptr + 2 * N, colu, out, N);
}